// Round 4
// baseline (581.248 us; speedup 1.0000x reference)
//
#include <hip/hip_runtime.h>
#include <hip/hip_bf16.h>

typedef float f32x4 __attribute__((ext_vector_type(4)));
typedef short bf16x8 __attribute__((ext_vector_type(8)));

#define HH 512
#define WW 512
#define NPLANES 48              // B*C = 16*3
#define KSIZE 23
#define NBLK (16 * 16 * NPLANES)
#define C1V 1.0e-4f             // 0.01^2
#define C2V 9.0e-4f             // 0.03^2

// LDS layout (ushort indices), ALIASED across phases:
//   stage:  SB [0,3960) SA [3960,7920) rows 0..54, pitch 72
//           OV [7920,8568) zero-filled (SA h-pass overflow rows 55..63 land
//           here; SB overflow lands in SA — finite always)
//           G  [8568,10616) 32x64 bf16, built per-block (swizzled)
//   h->v:   HB [0,8192) aliases SA/SB AFTER barrier2 (post h-pass reads);
//           G region is never aliased (v-pass reads it too).
// Total 10616 ushorts = 21232 B.
#define SB_O   0
#define SA_O   3960
#define OV_O   7920
#define G_O    8568
#define HB_O   0
#define HB_CH  2048
#define SPITCH 72
#define LDS_TOT 10616

// XOR bank swizzle within a pitch-64 region; preserves 8-ushort (16B) blocks.
#define SWZ(rho, k) ((k) ^ (((rho) & 7) << 3))

// pack two fp32 -> bf16 pair (lo = a, hi = b), RNE (v_cvt_pk_bf16_f32)
__device__ __forceinline__ unsigned cvtpk(float a, float b) {
    union { __hip_bfloat162 h; unsigned u; } cv;
    cv.h = __float22bfloat162_rn(make_float2(a, b));
    return cv.u;
}

// From packed bf16 pairs a,b build packed ab and a^2+b^2 (fp32 math on the
// ROUNDED bf16 values; ss takes one rounding of a^2+b^2 instead of two).
__device__ __forceinline__ void prod2(unsigned a, unsigned b,
                                      unsigned& pab, unsigned& pss) {
    float al = __uint_as_float(a << 16), ah = __uint_as_float(a & 0xffff0000u);
    float bl = __uint_as_float(b << 16), bh = __uint_as_float(b & 0xffff0000u);
    pab = cvtpk(al * bl, ah * bh);
    pss = cvtpk(al * al + bl * bl, ah * ah + bh * bh);
}

__device__ __forceinline__ f32x4 mfma16(uint4 a, uint4 b, f32x4 c) {
    union { uint4 u; bf16x8 h; } ua, ub;
    ua.u = a; ub.u = b;
    return __builtin_amdgcn_mfma_f32_16x16x32_bf16(ua.h, ub.h, c, 0, 0, 0);
}

// Single fused kernel (round-14): prep folded back in (per-block G build in
// the staging-latency slot), final folded in via last-block reduction.
// (256,6): VGPR cap 85; round-3 measured 36 VGPR, additions are small.
__global__ __launch_bounds__(256, 6) void ssim_main_kernel(
    const float* __restrict__ in, const float* __restrict__ tg,
    const float* __restrict__ w, float* __restrict__ partial,
    int* __restrict__ counter, float* __restrict__ out)
{
    __shared__ __align__(16) unsigned short lds[LDS_TOT];
    __shared__ float swsum[4];
    __shared__ int lastFlag;

    const int tid = threadIdx.x;
    const int wave = tid >> 6, lane = tid & 63;
    const int m = lane & 15, q = lane >> 4;

    const int blk = blockIdx.x;
    const int plane = blk >> 8;
    const int t2 = blk & 255;
    const int x0 = (t2 & 15) * 32 - 12;   // 16B-aligned frame origin
    const int y0 = (t2 >> 4) * 32 - 12;
    const float* __restrict__ inp = in + (size_t)plane * (HH * WW);
    const float* __restrict__ tgp = tg + (size_t)plane * (HH * WW);

    const bool interior = (x0 >= 0) && (y0 >= 0) && (x0 + 64 <= WW) && (y0 + 55 <= HH);

    // ---- phase A: ISSUE staging loads first (coalesced; latency hidden
    //      under the G-build / OV-fill below). 55 rows x 8 col-groups = 440
    //      tasks; thread handles tid and tid+256.
    float4 La[2][2], Lb[2][2];
    if (interior) {
        #pragma unroll
        for (int it = 0; it < 2; ++it) {
            int t = tid + it * 256;
            if (t < 440) {
                int r = t >> 3, c8 = (t & 7) << 3;
                const float4* pa = (const float4*)(inp + (y0 + r) * WW + x0 + c8);
                const float4* pb = (const float4*)(tgp + (y0 + r) * WW + x0 + c8);
                La[it][0] = pa[0]; La[it][1] = pa[1];
                Lb[it][0] = pb[0]; Lb[it][1] = pb[1];
            }
        }
    }

    // ---- phase B: build G in LDS (swizzled) + zero-fill overflow strip ----
    // G[r][k] = g[k-1-r] for k-1-r in [0,23), else 0; g = row-sums of the
    // separable normalized 2D kernel. Same math as the old prep kernel ->
    // bit-identical G.
    {
        float gv = 0.f;
        if (lane < KSIZE) {
            #pragma unroll
            for (int k = 0; k < KSIZE; ++k) gv += w[lane * KSIZE + k];
        }
        unsigned* gw = (unsigned*)lds + (G_O >> 1);
        const int kd = lane & 31;              // dword col (k = 2kd, 2kd+1)
        const int rh = (lane >> 5) << 2;       // 0 or 4
        #pragma unroll
        for (int i = 0; i < 4; ++i) {
            int r = wave * 8 + rh + i;
            int d0 = 2 * kd - 1 - r;
            float g0 = __shfl(gv, d0 & 63, 64);
            float g1 = __shfl(gv, (d0 + 1) & 63, 64);
            g0 = ((unsigned)d0 < (unsigned)KSIZE) ? g0 : 0.f;
            g1 = ((unsigned)(d0 + 1) < (unsigned)KSIZE) ? g1 : 0.f;
            gw[r * 32 + (kd ^ ((r & 7) << 2))] = cvtpk(g0, g1);
        }
    }
    if (tid < 81) {
        uint4 z; z.x = z.y = z.z = z.w = 0u;
        *(uint4*)&lds[OV_O + tid * 8] = z;
    }

    // ---- phase C: consume staging loads -> bf16 LDS ----
    if (interior) {
        #pragma unroll
        for (int it = 0; it < 2; ++it) {
            int t = tid + it * 256;
            if (t < 440) {
                int r = t >> 3, c8 = (t & 7) << 3;
                uint4 va, vb;
                va.x = cvtpk(La[it][0].x, La[it][0].y); va.y = cvtpk(La[it][0].z, La[it][0].w);
                va.z = cvtpk(La[it][1].x, La[it][1].y); va.w = cvtpk(La[it][1].z, La[it][1].w);
                vb.x = cvtpk(Lb[it][0].x, Lb[it][0].y); vb.y = cvtpk(Lb[it][0].z, Lb[it][0].w);
                vb.z = cvtpk(Lb[it][1].x, Lb[it][1].y); vb.w = cvtpk(Lb[it][1].z, Lb[it][1].w);
                *(uint4*)&lds[SA_O + r * SPITCH + c8] = va;
                *(uint4*)&lds[SB_O + r * SPITCH + c8] = vb;
            }
        }
    } else {
        unsigned* ldsw = (unsigned*)lds;
        for (int t = tid; t < 55 * 32; t += 256) {
            int r = t >> 5, cd = t & 31;
            int gy = y0 + r, gx = x0 + cd * 2;
            float a0 = 0.f, a1 = 0.f, b0 = 0.f, b1 = 0.f;
            if (gy >= 0 && gy < HH) {
                const float* ri = inp + gy * WW;
                const float* rt = tgp + gy * WW;
                if ((unsigned)gx < (unsigned)WW)       { a0 = ri[gx];     b0 = rt[gx]; }
                if ((unsigned)(gx + 1) < (unsigned)WW) { a1 = ri[gx + 1]; b1 = rt[gx + 1]; }
            }
            ldsw[(SA_O >> 1) + r * 36 + cd] = cvtpk(a0, a1);
            ldsw[(SB_O >> 1) + r * 36 + cd] = cvtpk(b0, b1);
        }
    }
    __syncthreads();   // barrier1: staging + G + OV visible

    // ---- h-pass (MFMA): wave = M-tile (frame rows wave*16..+15). Rows
    //      55..63 read OV zeros / SA junk — finite, killed by zero G taps.
    f32x4 acc[4][2];
    const f32x4 zz = {0.f, 0.f, 0.f, 0.f};
    #pragma unroll
    for (int ch = 0; ch < 4; ++ch) { acc[ch][0] = zz; acc[ch][1] = zz; }

    #pragma unroll
    for (int ks = 0; ks < 2; ++ks) {
        const int off = (wave * 16 + m) * SPITCH + ks * 32 + q * 8;
        uint4 ua = *(const uint4*)&lds[SA_O + off];
        uint4 ub = *(const uint4*)&lds[SB_O + off];
        uint4 uab, uss;
        prod2(ua.x, ub.x, uab.x, uss.x);
        prod2(ua.y, ub.y, uab.y, uss.y);
        prod2(ua.z, ub.z, uab.z, uss.z);
        prod2(ua.w, ub.w, uab.w, uss.w);
        #pragma unroll
        for (int nc = 0; nc < 2; ++nc) {
            const int gr = nc * 16 + m;
            uint4 gf = *(const uint4*)&lds[G_O + gr * 64 + SWZ(gr, ks * 32 + q * 8)];
            acc[0][nc] = mfma16(ua,  gf, acc[0][nc]);
            acc[1][nc] = mfma16(ub,  gf, acc[1][nc]);
            acc[2][nc] = mfma16(uss, gf, acc[2][nc]);
            acc[3][nc] = mfma16(uab, gf, acc[3][nc]);
        }
    }
    __syncthreads();   // barrier2: all SA/SB reads done -> HB may alias them

    // D frag: col = lane&15 (+nc*16), row = q*4 + reg (+wave*16). hb[ch][col][row].
    #pragma unroll
    for (int ch = 0; ch < 4; ++ch)
        #pragma unroll
        for (int nc = 0; nc < 2; ++nc) {
            f32x4 a = acc[ch][nc];
            uint2 pk;
            pk.x = cvtpk(a[0], a[1]);
            pk.y = cvtpk(a[2], a[3]);
            const int col = nc * 16 + m;
            const int rb = wave * 16 + q * 4;
            *(uint2*)&lds[HB_O + ch * HB_CH + col * 64 + SWZ(col, rb)] = pk;
        }
    __syncthreads();   // barrier3: HB visible

    // ---- v-pass (MFMA): wave = output quadrant (mrow, nc2) ----
    const int mrow = wave >> 1, nc2 = wave & 1;
    f32x4 av[4];
    #pragma unroll
    for (int ch = 0; ch < 4; ++ch) av[ch] = zz;

    #pragma unroll
    for (int ks = 0; ks < 2; ++ks) {
        const int ar = mrow * 16 + m;
        uint4 ga = *(const uint4*)&lds[G_O + ar * 64 + SWZ(ar, ks * 32 + q * 8)];
        #pragma unroll
        for (int ch = 0; ch < 4; ++ch) {
            const int col = nc2 * 16 + m;
            uint4 ub = *(const uint4*)&lds[HB_O + ch * HB_CH + col * 64 + SWZ(col, ks * 32 + q * 8)];
            av[ch] = mfma16(ga, ub, av[ch]);
        }
    }

    // ---- SSIM map on 4 px/lane + reduction ----
    float lsum = 0.f;
    #pragma unroll
    for (int i = 0; i < 4; ++i) {
        float vx = av[0][i], vt = av[1][i];
        float vss = av[2][i], vxt = av[3][i];
        float m1s = vx * vx, m2s = vt * vt, m12 = vx * vt;
        float sss = vss - m1s - m2s;          // s1 + s2
        float s12 = vxt - m12;
        float num = (2.f * m12 + C1V) * (2.f * s12 + C2V);
        float den = (m1s + m2s + C1V) * (sss + C2V);
        lsum += num * __builtin_amdgcn_rcpf(den);   // den > 0 for this data
    }
    #pragma unroll
    for (int off = 32; off > 0; off >>= 1)
        lsum += __shfl_down(lsum, off, 64);
    if (lane == 0) swsum[wave] = lsum;
    __syncthreads();

    // ---- last-block reduction (folds the old final kernel) ----
    if (tid == 0) {
        partial[blk] = swsum[0] + swsum[1] + swsum[2] + swsum[3];
        __threadfence();                         // release partial store
        int old = atomicAdd(counter, 1);         // device-scope
        lastFlag = (old == NBLK - 1);
    }
    __syncthreads();
    if (lastFlag) {
        __threadfence();                         // acquire all partials
        float s = 0.f;
        const float4* p4 = (const float4*)partial;
        for (int i = tid; i < NBLK / 4; i += 256) {
            float4 v = p4[i];
            s += (v.x + v.y) + (v.z + v.w);
        }
        #pragma unroll
        for (int off = 32; off > 0; off >>= 1)
            s += __shfl_down(s, off, 64);
        __syncthreads();                         // swsum reuse safe
        if (lane == 0) swsum[wave] = s;
        __syncthreads();
        if (tid == 0)
            out[0] = 1.0f - (swsum[0] + swsum[1] + swsum[2] + swsum[3])
                            * (1.0f / ((float)NPLANES * HH * WW));
    }
}

extern "C" void kernel_launch(void* const* d_in, const int* in_sizes, int n_in,
                              void* d_out, int out_size, void* d_ws, size_t ws_size,
                              hipStream_t stream) {
    const float* inp = (const float*)d_in[0];
    const float* tgt = (const float*)d_in[1];
    const float* wgt = (const float*)d_in[2];
    float* out = (float*)d_out;
    float* partial = (float*)d_ws;                       // NBLK floats
    int* counter = (int*)((char*)d_ws + NBLK * sizeof(float));

    hipMemsetAsync(counter, 0, sizeof(int), stream);     // per-call re-arm
    ssim_main_kernel<<<NBLK, 256, 0, stream>>>(inp, tgt, wgt, partial,
                                               counter, out);
}

// Round 5
// 167.821 us; speedup vs baseline: 3.4635x; 3.4635x over previous
//
#include <hip/hip_runtime.h>
#include <hip/hip_bf16.h>

typedef float f32x4 __attribute__((ext_vector_type(4)));
typedef short bf16x8 __attribute__((ext_vector_type(8)));

#define HH 512
#define WW 512
#define NPLANES 48              // B*C = 16*3
#define KSIZE 23
#define NBLK (8 * 16 * NPLANES) // 64-wide x 32-tall output tiles -> 6144
#define C1V 1.0e-4f             // 0.01^2
#define C2V 9.0e-4f             // 0.03^2

// Round-15: 32x64-out tiles, 512 threads / 8 waves. LDS (ushort idx):
//   G  [0,6656)      64 rows x pitch 104 (96 cols used), banded G[r][k]=g[k-1-r]
//   SB [6656,12376)  55 rows x pitch 104
//   SA [12376,18096)
//   OV [18096,19032) zero strip: SA h-pass overflow rows 55..63 land here;
//                    SB overflow lands in SA (finite always)
//   HB [6656,23040)  4ch x 64col x 64row, pitch 64 + SWZ; ALIASES SB/SA/OV
//                    after barrier2 (G never aliased - v-pass reads it)
// Total 23040 ush = 46080 B -> 3 blocks/CU x 8 waves = 24 waves/CU (same
// occupancy cap as round-3's 6x4, with half the per-px fixed costs).
// Pitch 104 (odd multiple of 8): row stride = 52 dwords = 20 mod 32 banks ->
// 16-row fragment reads are 2-way (free), NO swizzle arithmetic needed.
#define G_O    0
#define SB_O   6656
#define SA_O   12376
#define OV_O   18096
#define HB_O   6656
#define HB_CH  4096
#define SPITCH 104
#define SROWS  55
#define LDS_TOT 23040

// XOR bank swizzle for the pitch-64 HB region; preserves 8-ushort blocks.
#define SWZ(rho, k) ((k) ^ (((rho) & 7) << 3))

// pack two fp32 -> bf16 pair (lo = a, hi = b), RNE (v_cvt_pk_bf16_f32)
__device__ __forceinline__ unsigned cvtpk(float a, float b) {
    union { __hip_bfloat162 h; unsigned u; } cv;
    cv.h = __float22bfloat162_rn(make_float2(a, b));
    return cv.u;
}

// From packed bf16 pairs a,b build packed ab and a^2+b^2.
__device__ __forceinline__ void prod2(unsigned a, unsigned b,
                                      unsigned& pab, unsigned& pss) {
    float al = __uint_as_float(a << 16), ah = __uint_as_float(a & 0xffff0000u);
    float bl = __uint_as_float(b << 16), bh = __uint_as_float(b & 0xffff0000u);
    pab = cvtpk(al * bl, ah * bh);
    pss = cvtpk(al * al + bl * bl, ah * ah + bh * bh);
}

__device__ __forceinline__ f32x4 mfma16(uint4 a, uint4 b, f32x4 c) {
    union { uint4 u; bf16x8 h; } ua, ub;
    ua.u = a; ub.u = b;
    return __builtin_amdgcn_mfma_f32_16x16x32_bf16(ua.h, ub.h, c, 0, 0, 0);
}

// ---- prep: build banded G (64 rows x 48 dword-cols, LINEAR) once ----
// G[r][k] = g[k-1-r] for k-1-r in [0,23), else 0; g = row-sums of the
// normalized 2D kernel (separable 1D tap). 12 blocks x 256 = 3072 dwords.
__global__ __launch_bounds__(256) void ssim_prep_kernel(
    const float* __restrict__ w, unsigned* __restrict__ Gg)
{
    const int tid = threadIdx.x, lane = tid & 63;
    float gv = 0.f;
    if (lane < KSIZE) {
        #pragma unroll
        for (int k = 0; k < KSIZE; ++k) gv += w[lane * KSIZE + k];
    }
    const int idx = blockIdx.x * 256 + tid;     // [0, 3072)
    const int r = idx / 48, kd = idx % 48;
    const int d0 = 2 * kd - 1 - r;
    float g0 = __shfl(gv, d0 & 63, 64);
    float g1 = __shfl(gv, (d0 + 1) & 63, 64);
    g0 = ((unsigned)d0 < (unsigned)KSIZE) ? g0 : 0.f;
    g1 = ((unsigned)(d0 + 1) < (unsigned)KSIZE) ? g1 : 0.f;
    Gg[r * 48 + kd] = cvtpk(g0, g1);
}

// (512,6): 3 blocks/CU target -> 24 waves/CU; VGPR cap ~85 (round-3 measured
// 36 at the same inner math; acc is still 32 regs).
__global__ __launch_bounds__(512, 6) void ssim_main_kernel(
    const float* __restrict__ in, const float* __restrict__ tg,
    const unsigned* __restrict__ Gg, float* __restrict__ partial)
{
    __shared__ __align__(16) unsigned short lds[LDS_TOT];
    __shared__ float swsum[8];

    const int tid = threadIdx.x;
    const int wave = tid >> 6, lane = tid & 63;
    const int m = lane & 15, q = lane >> 4;

    const int blk = blockIdx.x;
    const int plane = blk >> 7;            // 128 tiles/plane
    const int t2 = blk & 127;
    const int tx = t2 & 7, ty = t2 >> 3;
    const int x0 = tx * 64 - 12;           // 16B-aligned frame origin
    const int y0 = ty * 32 - 12;
    const float* __restrict__ inp = in + (size_t)plane * (HH * WW);
    const float* __restrict__ tgp = tg + (size_t)plane * (HH * WW);

    const bool interior = (x0 >= 0) && (y0 >= 0) &&
                          (x0 + 96 <= WW) && (y0 + SROWS <= HH);

    // ---- phase A: ISSUE staging loads (coalesced; latency hidden under
    //      the G-copy below). 55 rows x 12 col-groups(8) = 660 tasks.
    float4 La[2][2], Lb[2][2];
    if (interior) {
        {   // t = tid (all 512 < 660)
            int r = tid / 12, c8 = (tid % 12) << 3;
            const float4* pa = (const float4*)(inp + (y0 + r) * WW + x0 + c8);
            const float4* pb = (const float4*)(tgp + (y0 + r) * WW + x0 + c8);
            La[0][0] = pa[0]; La[0][1] = pa[1];
            Lb[0][0] = pb[0]; Lb[0][1] = pb[1];
        }
        if (tid < 148) {   // t = tid + 512
            int t = tid + 512;
            int r = t / 12, c8 = (t % 12) << 3;
            const float4* pa = (const float4*)(inp + (y0 + r) * WW + x0 + c8);
            const float4* pb = (const float4*)(tgp + (y0 + r) * WW + x0 + c8);
            La[1][0] = pa[0]; La[1][1] = pa[1];
            Lb[1][0] = pb[0]; Lb[1][1] = pb[1];
        }
    }

    // ---- phase B: copy banded G into LDS + zero the overflow strip ----
    {   // 64 rows x 12 uint4-groups = 768 tasks
        int r = tid / 12, c = tid % 12;
        uint4 g4 = *(const uint4*)(Gg + r * 48 + c * 4);
        *(uint4*)&lds[G_O + r * SPITCH + c * 8] = g4;
        if (tid < 256) {
            int t = tid + 512;
            int r2 = t / 12, c2 = t % 12;
            uint4 h4 = *(const uint4*)(Gg + r2 * 48 + c2 * 4);
            *(uint4*)&lds[G_O + r2 * SPITCH + c2 * 8] = h4;
        }
    }
    if (tid < 117) {   // 936 ushorts = 117 uint4
        uint4 z; z.x = z.y = z.z = z.w = 0u;
        *(uint4*)&lds[OV_O + tid * 8] = z;
    }

    // ---- phase C: consume staging loads -> bf16 LDS ----
    if (interior) {
        {
            int r = tid / 12, c8 = (tid % 12) << 3;
            uint4 va, vb;
            va.x = cvtpk(La[0][0].x, La[0][0].y); va.y = cvtpk(La[0][0].z, La[0][0].w);
            va.z = cvtpk(La[0][1].x, La[0][1].y); va.w = cvtpk(La[0][1].z, La[0][1].w);
            vb.x = cvtpk(Lb[0][0].x, Lb[0][0].y); vb.y = cvtpk(Lb[0][0].z, Lb[0][0].w);
            vb.z = cvtpk(Lb[0][1].x, Lb[0][1].y); vb.w = cvtpk(Lb[0][1].z, Lb[0][1].w);
            *(uint4*)&lds[SA_O + r * SPITCH + c8] = va;
            *(uint4*)&lds[SB_O + r * SPITCH + c8] = vb;
        }
        if (tid < 148) {
            int t = tid + 512;
            int r = t / 12, c8 = (t % 12) << 3;
            uint4 va, vb;
            va.x = cvtpk(La[1][0].x, La[1][0].y); va.y = cvtpk(La[1][0].z, La[1][0].w);
            va.z = cvtpk(La[1][1].x, La[1][1].y); va.w = cvtpk(La[1][1].z, La[1][1].w);
            vb.x = cvtpk(Lb[1][0].x, Lb[1][0].y); vb.y = cvtpk(Lb[1][0].z, Lb[1][0].w);
            vb.z = cvtpk(Lb[1][1].x, Lb[1][1].y); vb.w = cvtpk(Lb[1][1].z, Lb[1][1].w);
            *(uint4*)&lds[SA_O + r * SPITCH + c8] = va;
            *(uint4*)&lds[SB_O + r * SPITCH + c8] = vb;
        }
    } else {
        unsigned* ldsw = (unsigned*)lds;
        for (int t = tid; t < SROWS * 48; t += 512) {
            int r = t / 48, cd = t % 48;
            int gy = y0 + r, gx = x0 + cd * 2;
            float a0 = 0.f, a1 = 0.f, b0 = 0.f, b1 = 0.f;
            if (gy >= 0 && gy < HH) {
                const float* ri = inp + gy * WW;
                const float* rt = tgp + gy * WW;
                if ((unsigned)gx < (unsigned)WW)       { a0 = ri[gx];     b0 = rt[gx]; }
                if ((unsigned)(gx + 1) < (unsigned)WW) { a1 = ri[gx + 1]; b1 = rt[gx + 1]; }
            }
            ldsw[(SA_O >> 1) + r * 52 + cd] = cvtpk(a0, a1);
            ldsw[(SB_O >> 1) + r * 52 + cd] = cvtpk(b0, b1);
        }
    }
    __syncthreads();   // barrier1: staging + G + OV visible

    // ---- h-pass (MFMA): wave = (wg, wt). wg selects out-col half (G rows
    //      wg*32..+31) and the 2 live K-steps of the band (A: ks{0,1},
    //      B: ks{1,2}); wt = M-tile (frame rows wt*16..+15). Rows 55..63
    //      read OV zeros / SA junk - finite, killed by zero G taps.
    const int wg = wave >> 2, wt = wave & 3;
    f32x4 acc[4][2];
    const f32x4 zz = {0.f, 0.f, 0.f, 0.f};
    #pragma unroll
    for (int ch = 0; ch < 4; ++ch) { acc[ch][0] = zz; acc[ch][1] = zz; }

    #pragma unroll
    for (int ksi = 0; ksi < 2; ++ksi) {
        const int ksel = wg + ksi;
        const int off = (wt * 16 + m) * SPITCH + ksel * 32 + q * 8;
        uint4 ua = *(const uint4*)&lds[SA_O + off];
        uint4 ub = *(const uint4*)&lds[SB_O + off];
        uint4 uab, uss;
        prod2(ua.x, ub.x, uab.x, uss.x);
        prod2(ua.y, ub.y, uab.y, uss.y);
        prod2(ua.z, ub.z, uab.z, uss.z);
        prod2(ua.w, ub.w, uab.w, uss.w);
        #pragma unroll
        for (int nc = 0; nc < 2; ++nc) {
            const int gr = wg * 32 + nc * 16 + m;
            uint4 gf = *(const uint4*)&lds[G_O + gr * SPITCH + ksel * 32 + q * 8];
            acc[0][nc] = mfma16(ua,  gf, acc[0][nc]);
            acc[1][nc] = mfma16(ub,  gf, acc[1][nc]);
            acc[2][nc] = mfma16(uss, gf, acc[2][nc]);
            acc[3][nc] = mfma16(uab, gf, acc[3][nc]);
        }
    }
    __syncthreads();   // barrier2: SA/SB reads done -> HB may alias them

    // D frag: out-col = lane&15 (+nc*16+wg*32), h-row = q*4+reg (+wt*16).
    #pragma unroll
    for (int ch = 0; ch < 4; ++ch)
        #pragma unroll
        for (int nc = 0; nc < 2; ++nc) {
            f32x4 a = acc[ch][nc];
            uint2 pk;
            pk.x = cvtpk(a[0], a[1]);
            pk.y = cvtpk(a[2], a[3]);
            const int col = wg * 32 + nc * 16 + m;
            const int rb = wt * 16 + q * 4;
            *(uint2*)&lds[HB_O + ch * HB_CH + col * 64 + SWZ(col, rb)] = pk;
        }
    __syncthreads();   // barrier3: HB visible

    // ---- v-pass (MFMA): wave = output quadrant (mrow 0..1, nc2 0..3);
    //      G taps: top-left 32x64 sub-band of the same G.
    const int mrow = wave >> 2, nc2 = wave & 3;
    f32x4 av[4];
    #pragma unroll
    for (int ch = 0; ch < 4; ++ch) av[ch] = zz;

    #pragma unroll
    for (int ks = 0; ks < 2; ++ks) {
        uint4 ga = *(const uint4*)&lds[G_O + (mrow * 16 + m) * SPITCH + ks * 32 + q * 8];
        #pragma unroll
        for (int ch = 0; ch < 4; ++ch) {
            const int col = nc2 * 16 + m;
            uint4 ub = *(const uint4*)&lds[HB_O + ch * HB_CH + col * 64 + SWZ(col, ks * 32 + q * 8)];
            av[ch] = mfma16(ga, ub, av[ch]);
        }
    }

    // ---- SSIM map on 4 px/lane + reduction ----
    float lsum = 0.f;
    #pragma unroll
    for (int i = 0; i < 4; ++i) {
        float vx = av[0][i], vt = av[1][i];
        float vss = av[2][i], vxt = av[3][i];
        float m1s = vx * vx, m2s = vt * vt, m12 = vx * vt;
        float sss = vss - m1s - m2s;          // s1 + s2
        float s12 = vxt - m12;
        float num = (2.f * m12 + C1V) * (2.f * s12 + C2V);
        float den = (m1s + m2s + C1V) * (sss + C2V);
        lsum += num * __builtin_amdgcn_rcpf(den);   // den > 0 for this data
    }
    #pragma unroll
    for (int off = 32; off > 0; off >>= 1)
        lsum += __shfl_down(lsum, off, 64);
    if (lane == 0) swsum[wave] = lsum;
    __syncthreads();
    if (tid == 0)
        partial[blk] = ((swsum[0] + swsum[1]) + (swsum[2] + swsum[3]))
                     + ((swsum[4] + swsum[5]) + (swsum[6] + swsum[7]));
}

__global__ __launch_bounds__(256) void ssim_final_kernel(
    const float* __restrict__ partial, float* __restrict__ out)
{
    __shared__ float swsum[4];
    const int tid = threadIdx.x;
    float s = 0.f;
    const float4* p4 = (const float4*)partial;
    for (int i = tid; i < NBLK / 4; i += 256) {
        float4 v = p4[i];
        s += (v.x + v.y) + (v.z + v.w);
    }
    #pragma unroll
    for (int off = 32; off > 0; off >>= 1)
        s += __shfl_down(s, off, 64);
    if ((tid & 63) == 0) swsum[tid >> 6] = s;
    __syncthreads();
    if (tid == 0)
        out[0] = 1.0f - (swsum[0] + swsum[1] + swsum[2] + swsum[3])
                        * (1.0f / ((float)NPLANES * HH * WW));
}

extern "C" void kernel_launch(void* const* d_in, const int* in_sizes, int n_in,
                              void* d_out, int out_size, void* d_ws, size_t ws_size,
                              hipStream_t stream) {
    const float* inp = (const float*)d_in[0];
    const float* tgt = (const float*)d_in[1];
    const float* wgt = (const float*)d_in[2];
    float* out = (float*)d_out;
    float* partial = (float*)d_ws;                       // NBLK floats (24 KB)
    unsigned* Gg = (unsigned*)((char*)d_ws + NBLK * sizeof(float));  // 12 KB

    ssim_prep_kernel<<<12, 256, 0, stream>>>(wgt, Gg);
    ssim_main_kernel<<<NBLK, 512, 0, stream>>>(inp, tgt, Gg, partial);
    ssim_final_kernel<<<1, 256, 0, stream>>>(partial, out);
}

// Round 6
// 153.170 us; speedup vs baseline: 3.7948x; 1.0956x over previous
//
#include <hip/hip_runtime.h>
#include <hip/hip_bf16.h>

typedef float f32x4 __attribute__((ext_vector_type(4)));
typedef short bf16x8 __attribute__((ext_vector_type(8)));

#define HH 512
#define WW 512
#define NPLANES 48              // B*C = 16*3
#define KSIZE 23
#define NBLK (16 * 16 * NPLANES)
#define C1V 1.0e-4f             // 0.01^2
#define C2V 9.0e-4f             // 0.03^2

// LDS layout (ushort indices), ALIASED across phases:
//   stage:  SB [0,3960) SA [3960,7920) rows 0..54, pitch 72
//           OV [7920,8568) zero-filled (SA h-pass overflow rows 55..63 land
//           here; SB overflow lands in SA — finite always)
//           G  [8568,10616) 32x64 bf16, swizzled copy of prep buffer
//   h->v:   HB [0,8192) aliases SA/SB AFTER barrier2 (post h-pass reads);
//           G region is never aliased (v-pass reads it too).
// Total 10616 ushorts = 21232 B -> 7 blocks/CU at (256,7).
#define SB_O   0
#define SA_O   3960
#define OV_O   7920
#define G_O    8568
#define HB_O   0
#define HB_CH  2048
#define SPITCH 72
#define LDS_TOT 10616

// XOR bank swizzle within a pitch-64 region; preserves 8-ushort (16B) blocks.
#define SWZ(rho, k) ((k) ^ (((rho) & 7) << 3))

// pack two fp32 -> bf16 pair (lo = a, hi = b), RNE (v_cvt_pk_bf16_f32)
__device__ __forceinline__ unsigned cvtpk(float a, float b) {
    union { __hip_bfloat162 h; unsigned u; } cv;
    cv.h = __float22bfloat162_rn(make_float2(a, b));
    return cv.u;
}

// From packed bf16 pairs a,b build packed ab and a^2+b^2 (fp32 math on the
// ROUNDED bf16 values; ss takes one rounding of a^2+b^2 instead of two).
__device__ __forceinline__ void prod2(unsigned a, unsigned b,
                                      unsigned& pab, unsigned& pss) {
    float al = __uint_as_float(a << 16), ah = __uint_as_float(a & 0xffff0000u);
    float bl = __uint_as_float(b << 16), bh = __uint_as_float(b & 0xffff0000u);
    pab = cvtpk(al * bl, ah * bh);
    pss = cvtpk(al * al + bl * bl, ah * ah + bh * bh);
}

__device__ __forceinline__ f32x4 mfma16(uint4 a, uint4 b, f32x4 c) {
    union { uint4 u; bf16x8 h; } ua, ub;
    ua.u = a; ub.u = b;
    return __builtin_amdgcn_mfma_f32_16x16x32_bf16(ua.h, ub.h, c, 0, 0, 0);
}

// ---- prep: build G (32 rows x 64 k, bf16 pairs, LINEAR layout) once ----
// G[r][k] = g[k-1-r] for k-1-r in [0,23), else 0; g = row-sums of the 2D
// normalized kernel (separable 1D tap).
__global__ __launch_bounds__(64) void ssim_prep_kernel(
    const float* __restrict__ w, unsigned* __restrict__ Gg)
{
    const int lane = threadIdx.x;
    float gv = 0.f;
    if (lane < KSIZE) {
        #pragma unroll
        for (int k = 0; k < KSIZE; ++k) gv += w[lane * KSIZE + k];
    }
    for (int idx = lane; idx < 32 * 32; idx += 64) {
        int r = idx >> 5, kd = idx & 31;
        int d0 = 2 * kd - 1 - r;
        float g0 = __shfl(gv, d0 & 63, 64);
        float g1 = __shfl(gv, (d0 + 1) & 63, 64);
        g0 = ((unsigned)d0 < (unsigned)KSIZE) ? g0 : 0.f;
        g1 = ((unsigned)(d0 + 1) < (unsigned)KSIZE) ? g1 : 0.f;
        Gg[idx] = cvtpk(g0, g1);
    }
}

// (256,7): round-3 measured VGPR=36 (cap ~73 at 7 waves/EU) and LDS 21.5 KB
// (7 x 21.5 = 150.5 <= 160 KB) -> 7 blocks/CU, 28 waves/CU ceiling (was 6/24).
__global__ __launch_bounds__(256, 7) void ssim_main_kernel(
    const float* __restrict__ in, const float* __restrict__ tg,
    const unsigned* __restrict__ Gg, float* __restrict__ partial)
{
    __shared__ __align__(16) unsigned short lds[LDS_TOT];
    __shared__ float swsum[4];

    const int tid = threadIdx.x;
    const int wave = tid >> 6, lane = tid & 63;
    const int m = lane & 15, q = lane >> 4;

    // XCD-aware swizzle (8 XCDs, NBLK % 8 == 0 -> bijective): consecutive
    // tiles (which share 12-px halos) land on the SAME XCD's L2, cutting the
    // 1.5x halo re-fetch seen in round 3 (FETCH 144 MB vs 96 MB ideal).
    const int blk = (blockIdx.x & 7) * (NBLK / 8) + (blockIdx.x >> 3);
    const int plane = blk >> 8;
    const int t2 = blk & 255;
    const int x0 = (t2 & 15) * 32 - 12;   // 16B-aligned frame origin
    const int y0 = (t2 >> 4) * 32 - 12;
    const float* __restrict__ inp = in + (size_t)plane * (HH * WW);
    const float* __restrict__ tgp = tg + (size_t)plane * (HH * WW);

    const bool interior = (x0 >= 0) && (y0 >= 0) && (x0 + 64 <= WW) && (y0 + 55 <= HH);

    // ---- phase A: ISSUE staging loads first (coalesced; latency hidden
    //      under the G-copy / OV-fill below). 55 rows x 8 col-groups = 440
    //      tasks; thread handles tid and tid+256.
    float4 La[2][2], Lb[2][2];
    if (interior) {
        #pragma unroll
        for (int it = 0; it < 2; ++it) {
            int t = tid + it * 256;
            if (t < 440) {
                int r = t >> 3, c8 = (t & 7) << 3;
                const float4* pa = (const float4*)(inp + (y0 + r) * WW + x0 + c8);
                const float4* pb = (const float4*)(tgp + (y0 + r) * WW + x0 + c8);
                La[it][0] = pa[0]; La[it][1] = pa[1];
                Lb[it][0] = pb[0]; Lb[it][1] = pb[1];
            }
        }
    }

    // ---- phase B: copy G into LDS (swizzled) + zero-fill overflow strip ----
    {   // 256 threads x 1 uint4 = 1024 dwords = whole G
        int r = tid >> 3;                    // 0..31
        int dc = (tid & 7) << 2;             // dword col, multiple of 4
        uint4 g4 = *(const uint4*)(Gg + r * 32 + dc);
        *(uint4*)&lds[G_O + r * 64 + (((dc << 1)) ^ ((r & 7) << 3))] = g4;
    }
    if (tid < 81) {
        uint4 z; z.x = z.y = z.z = z.w = 0u;
        *(uint4*)&lds[OV_O + tid * 8] = z;
    }

    // ---- phase C: consume staging loads -> bf16 LDS ----
    if (interior) {
        #pragma unroll
        for (int it = 0; it < 2; ++it) {
            int t = tid + it * 256;
            if (t < 440) {
                int r = t >> 3, c8 = (t & 7) << 3;
                uint4 va, vb;
                va.x = cvtpk(La[it][0].x, La[it][0].y); va.y = cvtpk(La[it][0].z, La[it][0].w);
                va.z = cvtpk(La[it][1].x, La[it][1].y); va.w = cvtpk(La[it][1].z, La[it][1].w);
                vb.x = cvtpk(Lb[it][0].x, Lb[it][0].y); vb.y = cvtpk(Lb[it][0].z, Lb[it][0].w);
                vb.z = cvtpk(Lb[it][1].x, Lb[it][1].y); vb.w = cvtpk(Lb[it][1].z, Lb[it][1].w);
                *(uint4*)&lds[SA_O + r * SPITCH + c8] = va;
                *(uint4*)&lds[SB_O + r * SPITCH + c8] = vb;
            }
        }
    } else {
        unsigned* ldsw = (unsigned*)lds;
        for (int t = tid; t < 55 * 32; t += 256) {
            int r = t >> 5, cd = t & 31;
            int gy = y0 + r, gx = x0 + cd * 2;
            float a0 = 0.f, a1 = 0.f, b0 = 0.f, b1 = 0.f;
            if (gy >= 0 && gy < HH) {
                const float* ri = inp + gy * WW;
                const float* rt = tgp + gy * WW;
                if ((unsigned)gx < (unsigned)WW)       { a0 = ri[gx];     b0 = rt[gx]; }
                if ((unsigned)(gx + 1) < (unsigned)WW) { a1 = ri[gx + 1]; b1 = rt[gx + 1]; }
            }
            ldsw[(SA_O >> 1) + r * 36 + cd] = cvtpk(a0, a1);
            ldsw[(SB_O >> 1) + r * 36 + cd] = cvtpk(b0, b1);
        }
    }
    __syncthreads();   // barrier1: staging + G + OV visible

    // ---- h-pass (MFMA): wave = M-tile (frame rows wave*16..+15). Rows
    //      55..63 read OV zeros / SA junk — finite, killed by zero G taps.
    f32x4 acc[4][2];
    const f32x4 zz = {0.f, 0.f, 0.f, 0.f};
    #pragma unroll
    for (int ch = 0; ch < 4; ++ch) { acc[ch][0] = zz; acc[ch][1] = zz; }

    #pragma unroll
    for (int ks = 0; ks < 2; ++ks) {
        const int off = (wave * 16 + m) * SPITCH + ks * 32 + q * 8;
        uint4 ua = *(const uint4*)&lds[SA_O + off];
        uint4 ub = *(const uint4*)&lds[SB_O + off];
        uint4 uab, uss;
        prod2(ua.x, ub.x, uab.x, uss.x);
        prod2(ua.y, ub.y, uab.y, uss.y);
        prod2(ua.z, ub.z, uab.z, uss.z);
        prod2(ua.w, ub.w, uab.w, uss.w);
        #pragma unroll
        for (int nc = 0; nc < 2; ++nc) {
            const int gr = nc * 16 + m;
            uint4 gf = *(const uint4*)&lds[G_O + gr * 64 + SWZ(gr, ks * 32 + q * 8)];
            acc[0][nc] = mfma16(ua,  gf, acc[0][nc]);
            acc[1][nc] = mfma16(ub,  gf, acc[1][nc]);
            acc[2][nc] = mfma16(uss, gf, acc[2][nc]);
            acc[3][nc] = mfma16(uab, gf, acc[3][nc]);
        }
    }
    __syncthreads();   // barrier2: all SA/SB reads done -> HB may alias them

    // D frag: col = lane&15 (+nc*16), row = q*4 + reg (+wave*16). hb[ch][col][row].
    #pragma unroll
    for (int ch = 0; ch < 4; ++ch)
        #pragma unroll
        for (int nc = 0; nc < 2; ++nc) {
            f32x4 a = acc[ch][nc];
            uint2 pk;
            pk.x = cvtpk(a[0], a[1]);
            pk.y = cvtpk(a[2], a[3]);
            const int col = nc * 16 + m;
            const int rb = wave * 16 + q * 4;
            *(uint2*)&lds[HB_O + ch * HB_CH + col * 64 + SWZ(col, rb)] = pk;
        }
    __syncthreads();   // barrier3: HB visible

    // ---- v-pass (MFMA): wave = output quadrant (mrow, nc2) ----
    const int mrow = wave >> 1, nc2 = wave & 1;
    f32x4 av[4];
    #pragma unroll
    for (int ch = 0; ch < 4; ++ch) av[ch] = zz;

    #pragma unroll
    for (int ks = 0; ks < 2; ++ks) {
        const int ar = mrow * 16 + m;
        uint4 ga = *(const uint4*)&lds[G_O + ar * 64 + SWZ(ar, ks * 32 + q * 8)];
        #pragma unroll
        for (int ch = 0; ch < 4; ++ch) {
            const int col = nc2 * 16 + m;
            uint4 ub = *(const uint4*)&lds[HB_O + ch * HB_CH + col * 64 + SWZ(col, ks * 32 + q * 8)];
            av[ch] = mfma16(ga, ub, av[ch]);
        }
    }

    // ---- SSIM map on 4 px/lane + reduction ----
    float lsum = 0.f;
    #pragma unroll
    for (int i = 0; i < 4; ++i) {
        float vx = av[0][i], vt = av[1][i];
        float vss = av[2][i], vxt = av[3][i];
        float m1s = vx * vx, m2s = vt * vt, m12 = vx * vt;
        float sss = vss - m1s - m2s;          // s1 + s2
        float s12 = vxt - m12;
        float num = (2.f * m12 + C1V) * (2.f * s12 + C2V);
        float den = (m1s + m2s + C1V) * (sss + C2V);
        lsum += num * __builtin_amdgcn_rcpf(den);   // den > 0 for this data
    }
    #pragma unroll
    for (int off = 32; off > 0; off >>= 1)
        lsum += __shfl_down(lsum, off, 64);
    if (lane == 0) swsum[wave] = lsum;
    __syncthreads();
    if (tid == 0)
        partial[blk] = swsum[0] + swsum[1] + swsum[2] + swsum[3];
}

__global__ __launch_bounds__(256) void ssim_final_kernel(
    const float* __restrict__ partial, float* __restrict__ out)
{
    __shared__ float swsum[4];
    const int tid = threadIdx.x;
    float s = 0.f;
    const float4* p4 = (const float4*)partial;
    for (int i = tid; i < NBLK / 4; i += 256) {
        float4 v = p4[i];
        s += (v.x + v.y) + (v.z + v.w);
    }
    #pragma unroll
    for (int off = 32; off > 0; off >>= 1)
        s += __shfl_down(s, off, 64);
    if ((tid & 63) == 0) swsum[tid >> 6] = s;
    __syncthreads();
    if (tid == 0)
        out[0] = 1.0f - (swsum[0] + swsum[1] + swsum[2] + swsum[3])
                        * (1.0f / ((float)NPLANES * HH * WW));
}

extern "C" void kernel_launch(void* const* d_in, const int* in_sizes, int n_in,
                              void* d_out, int out_size, void* d_ws, size_t ws_size,
                              hipStream_t stream) {
    const float* inp = (const float*)d_in[0];
    const float* tgt = (const float*)d_in[1];
    const float* wgt = (const float*)d_in[2];
    float* out = (float*)d_out;
    float* partial = (float*)d_ws;                       // NBLK floats
    unsigned* Gg = (unsigned*)((char*)d_ws + NBLK * sizeof(float));  // 4 KB G

    ssim_prep_kernel<<<1, 64, 0, stream>>>(wgt, Gg);
    ssim_main_kernel<<<NBLK, 256, 0, stream>>>(inp, tgt, Gg, partial);
    ssim_final_kernel<<<1, 256, 0, stream>>>(partial, out);
}

// Round 8
// 146.848 us; speedup vs baseline: 3.9582x; 1.0431x over previous
//
#include <hip/hip_runtime.h>
#include <hip/hip_bf16.h>

typedef float f32x4 __attribute__((ext_vector_type(4)));
typedef _Float16 f16x8 __attribute__((ext_vector_type(8)));
typedef _Float16 f16x2 __attribute__((ext_vector_type(2)));
typedef __fp16 h16x2 __attribute__((ext_vector_type(2)));   // builtin's return type

#define HH 512
#define WW 512
#define NPLANES 48              // B*C = 16*3
#define KSIZE 23
#define NBLK (16 * 16 * NPLANES)
#define C1V 1.0e-4f             // 0.01^2
#define C2V 9.0e-4f             // 0.03^2

// LDS layout (ushort indices), ALIASED across phases:
//   stage:  SB [0,3960) SA [3960,7920) rows 0..54, pitch 72
//           OV [7920,8568) zero-filled (SA h-pass overflow rows 55..63 land
//           here; SB overflow lands in SA — finite always)
//           G  [8568,10616) 32x64 fp16, swizzled copy of prep buffer
//   h->v:   HB [0,8192) aliases SA/SB AFTER barrier2 (post h-pass reads);
//           G region is never aliased (v-pass reads it too).
// Total 10616 ushorts = 21232 B -> 7 blocks/CU at (256,7).
// Round-17: compute core bf16 -> fp16. Same MFMA rate/layout; packed
// v_pk_mul/fma_f16 kill the unpack-mul-repack chains in prod2 (~60 VALU/thr).
#define SB_O   0
#define SA_O   3960
#define OV_O   7920
#define G_O    8568
#define HB_O   0
#define HB_CH  2048
#define SPITCH 72
#define LDS_TOT 10616

// XOR bank swizzle within a pitch-64 region; preserves 8-ushort (16B) blocks.
#define SWZ(rho, k) ((k) ^ (((rho) & 7) << 3))

// pack two fp32 -> fp16 pair (lo = a, hi = b), RTZ (v_cvt_pkrtz_f16_f32, 1 inst)
__device__ __forceinline__ unsigned cvtpk(float a, float b) {
    union { h16x2 h; unsigned u; } cv;
    cv.h = __builtin_amdgcn_cvt_pkrtz(a, b);
    return cv.u;
}

// Packed fp16 products: pab = a*b, pss = a*a + b*b (v_pk_mul + v_pk_fma).
__device__ __forceinline__ void prod2(unsigned a, unsigned b,
                                      unsigned& pab, unsigned& pss) {
    union U { f16x2 h; unsigned u; } ua, ub, r1, r2;
    ua.u = a; ub.u = b;
    r1.h = ua.h * ub.h;
    r2.h = ua.h * ua.h + ub.h * ub.h;
    pab = r1.u; pss = r2.u;
}

__device__ __forceinline__ f32x4 mfma16(uint4 a, uint4 b, f32x4 c) {
    union { uint4 u; f16x8 h; } ua, ub;
    ua.u = a; ub.u = b;
    return __builtin_amdgcn_mfma_f32_16x16x32_f16(ua.h, ub.h, c, 0, 0, 0);
}

// ---- prep: build G (32 rows x 64 k, fp16 pairs, LINEAR layout) once ----
// G[r][k] = g[k-1-r] for k-1-r in [0,23), else 0; g = row-sums of the 2D
// normalized kernel (separable 1D tap).
__global__ __launch_bounds__(64) void ssim_prep_kernel(
    const float* __restrict__ w, unsigned* __restrict__ Gg)
{
    const int lane = threadIdx.x;
    float gv = 0.f;
    if (lane < KSIZE) {
        #pragma unroll
        for (int k = 0; k < KSIZE; ++k) gv += w[lane * KSIZE + k];
    }
    for (int idx = lane; idx < 32 * 32; idx += 64) {
        int r = idx >> 5, kd = idx & 31;
        int d0 = 2 * kd - 1 - r;
        float g0 = __shfl(gv, d0 & 63, 64);
        float g1 = __shfl(gv, (d0 + 1) & 63, 64);
        g0 = ((unsigned)d0 < (unsigned)KSIZE) ? g0 : 0.f;
        g1 = ((unsigned)(d0 + 1) < (unsigned)KSIZE) ? g1 : 0.f;
        Gg[idx] = cvtpk(g0, g1);
    }
}

// (256,7): measured VGPR=36 (cap ~73 at 7 waves/EU), LDS 21.5 KB
// (7 x 21.5 = 150.5 <= 160 KB) -> 7 blocks/CU, 28 waves/CU ceiling.
__global__ __launch_bounds__(256, 7) void ssim_main_kernel(
    const float* __restrict__ in, const float* __restrict__ tg,
    const unsigned* __restrict__ Gg, float* __restrict__ partial)
{
    __shared__ __align__(16) unsigned short lds[LDS_TOT];
    __shared__ float swsum[4];

    const int tid = threadIdx.x;
    const int wave = tid >> 6, lane = tid & 63;
    const int m = lane & 15, q = lane >> 4;

    // XCD-aware swizzle (8 XCDs, NBLK % 8 == 0 -> bijective): consecutive
    // tiles (sharing 12-px halos) land on the SAME XCD's L2. Round-6
    // measured: FETCH 144 -> 49 MB.
    const int blk = (blockIdx.x & 7) * (NBLK / 8) + (blockIdx.x >> 3);
    const int plane = blk >> 8;
    const int t2 = blk & 255;
    const int x0 = (t2 & 15) * 32 - 12;   // 16B-aligned frame origin
    const int y0 = (t2 >> 4) * 32 - 12;
    const float* __restrict__ inp = in + (size_t)plane * (HH * WW);
    const float* __restrict__ tgp = tg + (size_t)plane * (HH * WW);

    const bool interior = (x0 >= 0) && (y0 >= 0) && (x0 + 64 <= WW) && (y0 + 55 <= HH);

    // ---- phase A: ISSUE staging loads first (coalesced; latency hidden
    //      under the G-copy / OV-fill below). 55 rows x 8 col-groups = 440
    //      tasks; thread handles tid and tid+256.
    float4 La[2][2], Lb[2][2];
    if (interior) {
        #pragma unroll
        for (int it = 0; it < 2; ++it) {
            int t = tid + it * 256;
            if (t < 440) {
                int r = t >> 3, c8 = (t & 7) << 3;
                const float4* pa = (const float4*)(inp + (y0 + r) * WW + x0 + c8);
                const float4* pb = (const float4*)(tgp + (y0 + r) * WW + x0 + c8);
                La[it][0] = pa[0]; La[it][1] = pa[1];
                Lb[it][0] = pb[0]; Lb[it][1] = pb[1];
            }
        }
    }

    // ---- phase B: copy G into LDS (swizzled) + zero-fill overflow strip ----
    {   // 256 threads x 1 uint4 = 1024 dwords = whole G
        int r = tid >> 3;                    // 0..31
        int dc = (tid & 7) << 2;             // dword col, multiple of 4
        uint4 g4 = *(const uint4*)(Gg + r * 32 + dc);
        *(uint4*)&lds[G_O + r * 64 + (((dc << 1)) ^ ((r & 7) << 3))] = g4;
    }
    if (tid < 81) {
        uint4 z; z.x = z.y = z.z = z.w = 0u;
        *(uint4*)&lds[OV_O + tid * 8] = z;
    }

    // ---- phase C: consume staging loads -> fp16 LDS ----
    if (interior) {
        #pragma unroll
        for (int it = 0; it < 2; ++it) {
            int t = tid + it * 256;
            if (t < 440) {
                int r = t >> 3, c8 = (t & 7) << 3;
                uint4 va, vb;
                va.x = cvtpk(La[it][0].x, La[it][0].y); va.y = cvtpk(La[it][0].z, La[it][0].w);
                va.z = cvtpk(La[it][1].x, La[it][1].y); va.w = cvtpk(La[it][1].z, La[it][1].w);
                vb.x = cvtpk(Lb[it][0].x, Lb[it][0].y); vb.y = cvtpk(Lb[it][0].z, Lb[it][0].w);
                vb.z = cvtpk(Lb[it][1].x, Lb[it][1].y); vb.w = cvtpk(Lb[it][1].z, Lb[it][1].w);
                *(uint4*)&lds[SA_O + r * SPITCH + c8] = va;
                *(uint4*)&lds[SB_O + r * SPITCH + c8] = vb;
            }
        }
    } else {
        unsigned* ldsw = (unsigned*)lds;
        for (int t = tid; t < 55 * 32; t += 256) {
            int r = t >> 5, cd = t & 31;
            int gy = y0 + r, gx = x0 + cd * 2;
            float a0 = 0.f, a1 = 0.f, b0 = 0.f, b1 = 0.f;
            if (gy >= 0 && gy < HH) {
                const float* ri = inp + gy * WW;
                const float* rt = tgp + gy * WW;
                if ((unsigned)gx < (unsigned)WW)       { a0 = ri[gx];     b0 = rt[gx]; }
                if ((unsigned)(gx + 1) < (unsigned)WW) { a1 = ri[gx + 1]; b1 = rt[gx + 1]; }
            }
            ldsw[(SA_O >> 1) + r * 36 + cd] = cvtpk(a0, a1);
            ldsw[(SB_O >> 1) + r * 36 + cd] = cvtpk(b0, b1);
        }
    }
    __syncthreads();   // barrier1: staging + G + OV visible

    // ---- h-pass (MFMA): wave = M-tile (frame rows wave*16..+15). Rows
    //      55..63 read OV zeros / SA junk — finite fp16, killed by zero G taps.
    f32x4 acc[4][2];
    const f32x4 zz = {0.f, 0.f, 0.f, 0.f};
    #pragma unroll
    for (int ch = 0; ch < 4; ++ch) { acc[ch][0] = zz; acc[ch][1] = zz; }

    #pragma unroll
    for (int ks = 0; ks < 2; ++ks) {
        const int off = (wave * 16 + m) * SPITCH + ks * 32 + q * 8;
        uint4 ua = *(const uint4*)&lds[SA_O + off];
        uint4 ub = *(const uint4*)&lds[SB_O + off];
        uint4 uab, uss;
        prod2(ua.x, ub.x, uab.x, uss.x);
        prod2(ua.y, ub.y, uab.y, uss.y);
        prod2(ua.z, ub.z, uab.z, uss.z);
        prod2(ua.w, ub.w, uab.w, uss.w);
        #pragma unroll
        for (int nc = 0; nc < 2; ++nc) {
            const int gr = nc * 16 + m;
            uint4 gf = *(const uint4*)&lds[G_O + gr * 64 + SWZ(gr, ks * 32 + q * 8)];
            acc[0][nc] = mfma16(ua,  gf, acc[0][nc]);
            acc[1][nc] = mfma16(ub,  gf, acc[1][nc]);
            acc[2][nc] = mfma16(uss, gf, acc[2][nc]);
            acc[3][nc] = mfma16(uab, gf, acc[3][nc]);
        }
    }
    __syncthreads();   // barrier2: all SA/SB reads done -> HB may alias them

    // D frag: col = lane&15 (+nc*16), row = q*4 + reg (+wave*16). hb[ch][col][row].
    #pragma unroll
    for (int ch = 0; ch < 4; ++ch)
        #pragma unroll
        for (int nc = 0; nc < 2; ++nc) {
            f32x4 a = acc[ch][nc];
            uint2 pk;
            pk.x = cvtpk(a[0], a[1]);
            pk.y = cvtpk(a[2], a[3]);
            const int col = nc * 16 + m;
            const int rb = wave * 16 + q * 4;
            *(uint2*)&lds[HB_O + ch * HB_CH + col * 64 + SWZ(col, rb)] = pk;
        }
    __syncthreads();   // barrier3: HB visible

    // ---- v-pass (MFMA): wave = output quadrant (mrow, nc2) ----
    const int mrow = wave >> 1, nc2 = wave & 1;
    f32x4 av[4];
    #pragma unroll
    for (int ch = 0; ch < 4; ++ch) av[ch] = zz;

    #pragma unroll
    for (int ks = 0; ks < 2; ++ks) {
        const int ar = mrow * 16 + m;
        uint4 ga = *(const uint4*)&lds[G_O + ar * 64 + SWZ(ar, ks * 32 + q * 8)];
        #pragma unroll
        for (int ch = 0; ch < 4; ++ch) {
            const int col = nc2 * 16 + m;
            uint4 ub = *(const uint4*)&lds[HB_O + ch * HB_CH + col * 64 + SWZ(col, ks * 32 + q * 8)];
            av[ch] = mfma16(ga, ub, av[ch]);
        }
    }

    // ---- SSIM map on 4 px/lane + reduction ----
    float lsum = 0.f;
    #pragma unroll
    for (int i = 0; i < 4; ++i) {
        float vx = av[0][i], vt = av[1][i];
        float vss = av[2][i], vxt = av[3][i];
        float m1s = vx * vx, m2s = vt * vt, m12 = vx * vt;
        float sss = vss - m1s - m2s;          // s1 + s2
        float s12 = vxt - m12;
        float num = (2.f * m12 + C1V) * (2.f * s12 + C2V);
        float den = (m1s + m2s + C1V) * (sss + C2V);
        lsum += num * __builtin_amdgcn_rcpf(den);   // den > 0 for this data
    }
    #pragma unroll
    for (int off = 32; off > 0; off >>= 1)
        lsum += __shfl_down(lsum, off, 64);
    if (lane == 0) swsum[wave] = lsum;
    __syncthreads();
    if (tid == 0)
        partial[blk] = swsum[0] + swsum[1] + swsum[2] + swsum[3];
}

__global__ __launch_bounds__(256) void ssim_final_kernel(
    const float* __restrict__ partial, float* __restrict__ out)
{
    __shared__ float swsum[4];
    const int tid = threadIdx.x;
    float s = 0.f;
    const float4* p4 = (const float4*)partial;
    for (int i = tid; i < NBLK / 4; i += 256) {
        float4 v = p4[i];
        s += (v.x + v.y) + (v.z + v.w);
    }
    #pragma unroll
    for (int off = 32; off > 0; off >>= 1)
        s += __shfl_down(s, off, 64);
    if ((tid & 63) == 0) swsum[tid >> 6] = s;
    __syncthreads();
    if (tid == 0)
        out[0] = 1.0f - (swsum[0] + swsum[1] + swsum[2] + swsum[3])
                        * (1.0f / ((float)NPLANES * HH * WW));
}

extern "C" void kernel_launch(void* const* d_in, const int* in_sizes, int n_in,
                              void* d_out, int out_size, void* d_ws, size_t ws_size,
                              hipStream_t stream) {
    const float* inp = (const float*)d_in[0];
    const float* tgt = (const float*)d_in[1];
    const float* wgt = (const float*)d_in[2];
    float* out = (float*)d_out;
    float* partial = (float*)d_ws;                       // NBLK floats
    unsigned* Gg = (unsigned*)((char*)d_ws + NBLK * sizeof(float));  // 4 KB G

    ssim_prep_kernel<<<1, 64, 0, stream>>>(wgt, Gg);
    ssim_main_kernel<<<NBLK, 256, 0, stream>>>(inp, tgt, Gg, partial);
    ssim_final_kernel<<<1, 256, 0, stream>>>(partial, out);
}